// Round 1
// baseline (470.540 us; speedup 1.0000x reference)
//
#include <hip/hip_runtime.h>
#include <hip/hip_bf16.h>
#include <stdint.h>

#define S_LEN 2048
#define D_DIM 1024
#define NBATCH 8

typedef __attribute__((ext_vector_type(8))) short bf16x8;
typedef __attribute__((ext_vector_type(4))) float f32x4;

static __device__ __forceinline__ unsigned short f2bf(float f) {
  union { float f; unsigned int u; } v; v.f = f;
  unsigned int u = v.u;
  u += 0x7FFFu + ((u >> 16) & 1u);   // RNE
  return (unsigned short)(u >> 16);
}

typedef __attribute__((address_space(1))) void gvoid;
typedef __attribute__((address_space(3))) void lvoid;
static __device__ __forceinline__ void gload_lds16(const void* gp, void* lp) {
  __builtin_amdgcn_global_load_lds((gvoid*)gp, (lvoid*)lp, 16, 0, 0);
}

// ---------------- W [K=1024][N=1024] fp32 -> Wt [N][K] bf16 ----------------
__global__ __launch_bounds__(256) void k_convW(const float* __restrict__ W,
                                               unsigned short* __restrict__ Wt) {
  __shared__ __align__(16) unsigned short lds[64][72];
  const int tid = threadIdx.x;
  const int n0 = blockIdx.x * 64, k0 = blockIdx.y * 64;
  for (int i = 0; i < 4; ++i) {               // load 64(k) x 64(n) fp32, convert
    int c = i * 256 + tid;
    int r = c >> 4, c4 = (c & 15) * 4;
    float4 v = *(const float4*)(W + (size_t)(k0 + r) * 1024 + n0 + c4);
    unsigned short* p = &lds[r][c4];
    p[0] = f2bf(v.x); p[1] = f2bf(v.y); p[2] = f2bf(v.z); p[3] = f2bf(v.w);
  }
  __syncthreads();
  for (int i = 0; i < 2; ++i) {               // write transposed: Wt[n][k]
    int c = i * 256 + tid;
    int n = c >> 3, k8 = (c & 7) * 8;
    unsigned short tmp[8];
    for (int j = 0; j < 8; ++j) tmp[j] = lds[k8 + j][n];
    *(uint4*)(Wt + (size_t)(n0 + n) * 1024 + k0 + k8) = *(uint4*)tmp;
  }
}

// ---------------- F [S][D] bf16 -> Ft [D][S] bf16, per batch ----------------
__global__ __launch_bounds__(256) void k_transF(const unsigned short* __restrict__ F,
                                                unsigned short* __restrict__ Ft) {
  __shared__ __align__(16) unsigned short lds[64][72];
  const int tid = threadIdx.x;
  const int t0 = blockIdx.x * 64, d0 = blockIdx.y * 64;
  const unsigned short* Fb = F + (size_t)blockIdx.z * S_LEN * D_DIM;
  unsigned short* Ftb = Ft + (size_t)blockIdx.z * D_DIM * S_LEN;
  for (int i = 0; i < 2; ++i) {
    int c = i * 256 + tid;
    int r = c >> 3, d8 = (c & 7) * 8;
    *(uint4*)(&lds[r][d8]) = *(const uint4*)(Fb + (size_t)(t0 + r) * D_DIM + d0 + d8);
  }
  __syncthreads();
  for (int i = 0; i < 2; ++i) {
    int c = i * 256 + tid;
    int d = c >> 3, t8 = (c & 7) * 8;
    unsigned short tmp[8];
    for (int j = 0; j < 8; ++j) tmp[j] = lds[t8 + j][d];
    *(uint4*)(Ftb + (size_t)(d0 + d) * S_LEN + t0 + t8) = *(uint4*)tmp;
  }
}

// ---------------- GEMM1: F[16384][1024] = bf16( X @ W + b ) ----------------
__global__ __launch_bounds__(256) void k_gemm1(const float* __restrict__ X,
                                               const unsigned short* __restrict__ Wt,
                                               const float* __restrict__ bias,
                                               unsigned short* __restrict__ F) {
  __shared__ __align__(16) unsigned short As[128 * 32];
  __shared__ __align__(16) unsigned short Bs[128 * 32];
  const int tid = threadIdx.x, lane = tid & 63, wid = tid >> 6;
  const int wr = wid >> 1, wc = wid & 1;
  const int m0 = blockIdx.x * 128, n0 = blockIdx.y * 128;
  f32x4 acc[4][4] = {};
  const int ar = tid & 127, ah = (tid >> 7) * 16;   // A-staging: row, col-half
  for (int kt = 0; kt < 1024; kt += 32) {
    __syncthreads();
    { // stage A: fp32 -> bf16 reg-staged
      const float* src = X + (size_t)(m0 + ar) * 1024 + kt + ah;
      unsigned short tmp[16];
      for (int i = 0; i < 4; ++i) {
        float4 v = *(const float4*)(src + i * 4);
        tmp[i*4+0] = f2bf(v.x); tmp[i*4+1] = f2bf(v.y);
        tmp[i*4+2] = f2bf(v.z); tmp[i*4+3] = f2bf(v.w);
      }
      unsigned short* dst = &As[ar * 32 + ah];
      *(uint4*)(dst)     = *(uint4*)(tmp);
      *(uint4*)(dst + 8) = *(uint4*)(tmp + 8);
    }
    for (int j = 0; j < 2; ++j) { // stage B via global_load_lds (wave-uniform dest)
      int c = wid * 2 + j;
      int r = c * 16 + (lane >> 2), col = (lane & 3) * 8;
      gload_lds16(Wt + (size_t)(n0 + r) * 1024 + kt + col, ((char*)Bs) + c * 1024);
    }
    __syncthreads();
    bf16x8 a[4], b[4];
    const int k8 = (lane >> 4) * 8, rl = lane & 15;
    for (int m = 0; m < 4; ++m) a[m] = *(const bf16x8*)(&As[(wr*64 + m*16 + rl) * 32 + k8]);
    for (int n = 0; n < 4; ++n) b[n] = *(const bf16x8*)(&Bs[(wc*64 + n*16 + rl) * 32 + k8]);
    for (int m = 0; m < 4; ++m)
      for (int n = 0; n < 4; ++n)
        acc[m][n] = __builtin_amdgcn_mfma_f32_16x16x32_bf16(a[m], b[n], acc[m][n], 0, 0, 0);
  }
  const int r4 = (lane >> 4) * 4, cl = lane & 15;
  for (int m = 0; m < 4; ++m)
    for (int n = 0; n < 4; ++n) {
      int row = m0 + wr*64 + m*16 + r4;
      int col = n0 + wc*64 + n*16 + cl;
      float bv = bias[col];
      for (int j = 0; j < 4; ++j)
        F[(size_t)(row + j) * 1024 + col] = f2bf(acc[m][n][j] + bv);
    }
}

// ---------------- GEMM2: E[b] = F[b] @ F[b]^T + dist_bias, fp32 ----------------
__global__ __launch_bounds__(256) void k_gemm2(const unsigned short* __restrict__ F,
                                               float* __restrict__ E) {
  __shared__ __align__(16) unsigned short As[128 * 32];
  __shared__ __align__(16) unsigned short Bs[128 * 32];
  const int tid = threadIdx.x, lane = tid & 63, wid = tid >> 6;
  const int wr = wid >> 1, wc = wid & 1;
  const int i0 = blockIdx.y * 128, j0 = blockIdx.x * 128;
  const unsigned short* Fb = F + (size_t)blockIdx.z * S_LEN * D_DIM;
  float* Eb = E + (size_t)blockIdx.z * S_LEN * S_LEN;
  f32x4 acc[4][4] = {};
  for (int kt = 0; kt < 1024; kt += 32) {
    __syncthreads();
    for (int j = 0; j < 2; ++j) {
      int c = wid * 2 + j;
      int r = c * 16 + (lane >> 2), col = (lane & 3) * 8;
      gload_lds16(Fb + (size_t)(i0 + r) * D_DIM + kt + col, ((char*)As) + c * 1024);
      gload_lds16(Fb + (size_t)(j0 + r) * D_DIM + kt + col, ((char*)Bs) + c * 1024);
    }
    __syncthreads();
    bf16x8 a[4], b[4];
    const int k8 = (lane >> 4) * 8, rl = lane & 15;
    for (int m = 0; m < 4; ++m) a[m] = *(const bf16x8*)(&As[(wr*64 + m*16 + rl) * 32 + k8]);
    for (int n = 0; n < 4; ++n) b[n] = *(const bf16x8*)(&Bs[(wc*64 + n*16 + rl) * 32 + k8]);
    for (int m = 0; m < 4; ++m)
      for (int n = 0; n < 4; ++n)
        acc[m][n] = __builtin_amdgcn_mfma_f32_16x16x32_bf16(a[m], b[n], acc[m][n], 0, 0, 0);
  }
  const int r4 = (lane >> 4) * 4, cl = lane & 15;
  for (int m = 0; m < 4; ++m)
    for (int n = 0; n < 4; ++n) {
      int row = i0 + wr*64 + m*16 + r4;
      int col = j0 + wc*64 + n*16 + cl;
      for (int j = 0; j < 4; ++j) {
        int rr = row + j;
        int d = rr - col; d = d < 0 ? -d : d; d = d > 10 ? 10 : d;
        Eb[(size_t)rr * S_LEN + col] = acc[m][n][j] + (float)d * 0.01f;
      }
    }
}

// ---------------- row softmax, fp32 in-place -> bf16 (row stride 4096 bf16) ----------------
__global__ __launch_bounds__(256) void k_softmax(float* __restrict__ E) {
  float* row = E + (size_t)blockIdx.x * S_LEN;
  const int tid = threadIdx.x, lane = tid & 63, w = tid >> 6;
  float4 v0 = *(const float4*)(row + tid * 4);
  float4 v1 = *(const float4*)(row + 1024 + tid * 4);
  float mx = fmaxf(fmaxf(fmaxf(v0.x, v0.y), fmaxf(v0.z, v0.w)),
                   fmaxf(fmaxf(v1.x, v1.y), fmaxf(v1.z, v1.w)));
  for (int s = 32; s > 0; s >>= 1) mx = fmaxf(mx, __shfl_xor(mx, s));
  __shared__ float redm[4], reds[4];
  if (lane == 0) redm[w] = mx;
  __syncthreads();
  mx = fmaxf(fmaxf(redm[0], redm[1]), fmaxf(redm[2], redm[3]));
  float p[8];
  p[0] = __expf(v0.x - mx); p[1] = __expf(v0.y - mx);
  p[2] = __expf(v0.z - mx); p[3] = __expf(v0.w - mx);
  p[4] = __expf(v1.x - mx); p[5] = __expf(v1.y - mx);
  p[6] = __expf(v1.z - mx); p[7] = __expf(v1.w - mx);
  float sum = p[0]+p[1]+p[2]+p[3]+p[4]+p[5]+p[6]+p[7];
  for (int s = 32; s > 0; s >>= 1) sum += __shfl_xor(sum, s);
  if (lane == 0) reds[w] = sum;
  __syncthreads();
  sum = reds[0] + reds[1] + reds[2] + reds[3];
  float inv = 1.0f / sum;
  unsigned short* prow = (unsigned short*)row;   // in-place; barriers fence the RAW
  unsigned short h[8];
  for (int i = 0; i < 8; ++i) h[i] = f2bf(p[i] * inv);
  *(uint2*)(prow + tid * 4)        = *(uint2*)(h);
  *(uint2*)(prow + 1024 + tid * 4) = *(uint2*)(h + 4);
}

// ---------------- GEMM3: out[b] = P[b] @ F[b]  (A lda=4096 bf16, B = Ft) ----------------
__global__ __launch_bounds__(256) void k_gemm3(const unsigned short* __restrict__ P,
                                               const unsigned short* __restrict__ Ft,
                                               float* __restrict__ out) {
  __shared__ __align__(16) unsigned short As[128 * 32];
  __shared__ __align__(16) unsigned short Bs[128 * 32];
  const int tid = threadIdx.x, lane = tid & 63, wid = tid >> 6;
  const int wr = wid >> 1, wc = wid & 1;
  const int m0 = blockIdx.y * 128, n0 = blockIdx.x * 128;
  const unsigned short* Pb = P + (size_t)blockIdx.z * S_LEN * 4096;
  const unsigned short* Ftb = Ft + (size_t)blockIdx.z * D_DIM * S_LEN;
  float* outb = out + (size_t)blockIdx.z * S_LEN * D_DIM;
  f32x4 acc[4][4] = {};
  for (int kt = 0; kt < S_LEN; kt += 32) {
    __syncthreads();
    for (int j = 0; j < 2; ++j) {
      int c = wid * 2 + j;
      int r = c * 16 + (lane >> 2), col = (lane & 3) * 8;
      gload_lds16(Pb + (size_t)(m0 + r) * 4096 + kt + col, ((char*)As) + c * 1024);
      gload_lds16(Ftb + (size_t)(n0 + r) * S_LEN + kt + col, ((char*)Bs) + c * 1024);
    }
    __syncthreads();
    bf16x8 a[4], b[4];
    const int k8 = (lane >> 4) * 8, rl = lane & 15;
    for (int m = 0; m < 4; ++m) a[m] = *(const bf16x8*)(&As[(wr*64 + m*16 + rl) * 32 + k8]);
    for (int n = 0; n < 4; ++n) b[n] = *(const bf16x8*)(&Bs[(wc*64 + n*16 + rl) * 32 + k8]);
    for (int m = 0; m < 4; ++m)
      for (int n = 0; n < 4; ++n)
        acc[m][n] = __builtin_amdgcn_mfma_f32_16x16x32_bf16(a[m], b[n], acc[m][n], 0, 0, 0);
  }
  const int r4 = (lane >> 4) * 4, cl = lane & 15;
  for (int m = 0; m < 4; ++m)
    for (int n = 0; n < 4; ++n) {
      int row = m0 + wr*64 + m*16 + r4;
      int col = n0 + wc*64 + n*16 + cl;
      for (int j = 0; j < 4; ++j)
        outb[(size_t)(row + j) * D_DIM + col] = acc[m][n][j];
    }
}

extern "C" void kernel_launch(void* const* d_in, const int* in_sizes, int n_in,
                              void* d_out, int out_size, void* d_ws, size_t ws_size,
                              hipStream_t stream) {
  const float* x = (const float*)d_in[0];   // [8,2048,1024] fp32
  const float* W = (const float*)d_in[1];   // [1024,1024] fp32
  const float* b = (const float*)d_in[2];   // [1024] fp32
  float* out = (float*)d_out;               // [8,2048,1024] fp32

  // workspace layout (bytes): Wt 2MiB | F 32MiB | Ft 32MiB | E/P 128MiB  = 194MiB
  unsigned short* Wt = (unsigned short*)d_ws;
  unsigned short* F  = (unsigned short*)((char*)d_ws + (2ull  << 20));
  unsigned short* Ft = (unsigned short*)((char*)d_ws + (34ull << 20));
  float*          E  = (float*)         ((char*)d_ws + (66ull << 20));

  k_convW  <<<dim3(16, 16),      256, 0, stream>>>(W, Wt);
  k_gemm1  <<<dim3(128, 8),      256, 0, stream>>>(x, Wt, b, F);
  k_transF <<<dim3(32, 16, 8),   256, 0, stream>>>(F, Ft);
  k_gemm2  <<<dim3(16, 16, 8),   256, 0, stream>>>(F, E);
  k_softmax<<<dim3(16384),       256, 0, stream>>>(E);
  k_gemm3  <<<dim3(8, 16, 8),    256, 0, stream>>>((const unsigned short*)E, Ft, out);
}

// Round 2
// 383.596 us; speedup vs baseline: 1.2267x; 1.2267x over previous
//
#include <hip/hip_runtime.h>
#include <hip/hip_bf16.h>
#include <stdint.h>

typedef __attribute__((ext_vector_type(8))) short bf16x8;
typedef __attribute__((ext_vector_type(4))) float f32x4;
typedef unsigned short ushort_t;

static __device__ __forceinline__ unsigned short f2bf(float f) {
  union { float f; unsigned int u; } v; v.f = f;
  unsigned int u = v.u;
  u += 0x7FFFu + ((u >> 16) & 1u);   // RNE
  return (unsigned short)(u >> 16);
}
static __device__ __forceinline__ float bf2f(unsigned short h) {
  union { unsigned int u; float f; } v; v.u = ((unsigned int)h) << 16; return v.f;
}

typedef __attribute__((address_space(1))) void gvoid;
typedef __attribute__((address_space(3))) void lvoid;
static __device__ __forceinline__ void gload_lds16(const void* gp, void* lp) {
  __builtin_amdgcn_global_load_lds((gvoid*)gp, (lvoid*)lp, 16, 0, 0);
}

// ---------------- X fp32 -> Xb bf16 (16.7M elems) ----------------
__global__ __launch_bounds__(256) void k_convX(const float* __restrict__ X,
                                               unsigned short* __restrict__ Xb) {
  size_t i = ((size_t)blockIdx.x * 256 + threadIdx.x) * 8;
  const size_t stride = (size_t)4096 * 256 * 8;
  for (; i < (size_t)16777216; i += stride) {
    float4 v0 = *(const float4*)(X + i), v1 = *(const float4*)(X + i + 4);
    unsigned short h[8];
    h[0]=f2bf(v0.x); h[1]=f2bf(v0.y); h[2]=f2bf(v0.z); h[3]=f2bf(v0.w);
    h[4]=f2bf(v1.x); h[5]=f2bf(v1.y); h[6]=f2bf(v1.z); h[7]=f2bf(v1.w);
    *(uint4*)(Xb + i) = *(uint4*)h;
  }
}

// ---------------- W [K=1024][N=1024] fp32 -> Wt [N][K] bf16 ----------------
__global__ __launch_bounds__(256) void k_convW(const float* __restrict__ W,
                                               unsigned short* __restrict__ Wt) {
  __shared__ __align__(16) unsigned short lds[64][72];
  const int tid = threadIdx.x;
  const int n0 = blockIdx.x * 64, k0 = blockIdx.y * 64;
  for (int i = 0; i < 4; ++i) {
    int c = i * 256 + tid;
    int r = c >> 4, c4 = (c & 15) * 4;
    float4 v = *(const float4*)(W + (size_t)(k0 + r) * 1024 + n0 + c4);
    unsigned short* p = &lds[r][c4];
    p[0] = f2bf(v.x); p[1] = f2bf(v.y); p[2] = f2bf(v.z); p[3] = f2bf(v.w);
  }
  __syncthreads();
  for (int i = 0; i < 2; ++i) {
    int c = i * 256 + tid;
    int n = c >> 3, k8 = (c & 7) * 8;
    unsigned short tmp[8];
    for (int j = 0; j < 8; ++j) tmp[j] = lds[k8 + j][n];
    *(uint4*)(Wt + (size_t)(n0 + n) * 1024 + k0 + k8) = *(uint4*)tmp;
  }
}

// ---------------- F [S][D] bf16 -> Ft [D][S] bf16, per batch ----------------
__global__ __launch_bounds__(256) void k_transF(const unsigned short* __restrict__ F,
                                                unsigned short* __restrict__ Ft) {
  __shared__ __align__(16) unsigned short lds[64][72];
  const int tid = threadIdx.x;
  const int t0 = blockIdx.x * 64, d0 = blockIdx.y * 64;
  const unsigned short* Fb = F + (size_t)blockIdx.z * 2048 * 1024;
  unsigned short* Ftb = Ft + (size_t)blockIdx.z * 1024 * 2048;
  for (int i = 0; i < 2; ++i) {
    int c = i * 256 + tid;
    int r = c >> 3, d8 = (c & 7) * 8;
    *(uint4*)(&lds[r][d8]) = *(const uint4*)(Fb + (size_t)(t0 + r) * 1024 + d0 + d8);
  }
  __syncthreads();
  for (int i = 0; i < 2; ++i) {
    int c = i * 256 + tid;
    int d = c >> 3, t8 = (c & 7) * 8;
    unsigned short tmp[8];
    for (int j = 0; j < 8; ++j) tmp[j] = lds[t8 + j][d];
    *(uint4*)(Ftb + (size_t)(d0 + d) * 2048 + t0 + t8) = *(uint4*)tmp;
  }
}

// =====================================================================
// 256x256 tile, BK=32, double-buffered LDS (64 KiB), 8 waves (2M x 4N),
// 2-phase schedule: STAGE(next, other buf) -> COMPUTE(cur) -> syncthreads.
// =====================================================================

#define GEMM_PREAMBLE                                                         \
  const int tid = threadIdx.x, lane = tid & 63, wid = tid >> 6;               \
  const int wr = wid >> 2, wc = wid & 3;                                      \
  const int rl = lane & 15, k8 = (lane >> 4) * 8;                             \
  f32x4 acc[8][4] = {};

// stage one 256x32 bf16 tile (16 KiB): 2 rounds x 8 waves; chunk=16 rows
#define STAGE_ONE(dst, src, ld, row0, kcol0)                                  \
  _Pragma("unroll") for (int r_ = 0; r_ < 2; ++r_) {                          \
    int chunk_ = r_ * 8 + wid;                                                \
    gload_lds16((src) + (size_t)((row0) + chunk_ * 16 + (lane >> 2)) * (ld)   \
                      + (kcol0) + (lane & 3) * 8,                             \
                (char*)(dst) + chunk_ * 1024);                                \
  }

#define COMPUTE_TILE(Abuf, Bbuf)                                              \
  {                                                                           \
    bf16x8 a_[8], b_[4];                                                      \
    _Pragma("unroll") for (int m_ = 0; m_ < 8; ++m_)                          \
      a_[m_] = *(const bf16x8*)((Abuf) + (wr * 128 + m_ * 16 + rl) * 32 + k8);\
    _Pragma("unroll") for (int n_ = 0; n_ < 4; ++n_)                          \
      b_[n_] = *(const bf16x8*)((Bbuf) + (wc * 64 + n_ * 16 + rl) * 32 + k8); \
    _Pragma("unroll") for (int m_ = 0; m_ < 8; ++m_)                          \
      _Pragma("unroll") for (int n_ = 0; n_ < 4; ++n_)                        \
        acc[m_][n_] = __builtin_amdgcn_mfma_f32_16x16x32_bf16(                \
            a_[m_], b_[n_], acc[m_][n_], 0, 0, 0);                            \
  }

#define GEMM_MAIN(Asrc, Alda, arow0, Bsrc, Blda, brow0, NT)                   \
  __shared__ __align__(16) unsigned short As[2][8192];                        \
  __shared__ __align__(16) unsigned short Bs[2][8192];                        \
  STAGE_ONE(As[0], Asrc, Alda, arow0, 0)                                      \
  STAGE_ONE(Bs[0], Bsrc, Blda, brow0, 0)                                      \
  __syncthreads();                                                            \
  int cur = 0;                                                                \
  for (int t = 0; t < (NT) - 1; ++t) {                                        \
    STAGE_ONE(As[cur ^ 1], Asrc, Alda, arow0, (t + 1) * 32)                   \
    STAGE_ONE(Bs[cur ^ 1], Bsrc, Blda, brow0, (t + 1) * 32)                   \
    COMPUTE_TILE(As[cur], Bs[cur])                                            \
    __syncthreads();                                                          \
    cur ^= 1;                                                                 \
  }                                                                           \
  COMPUTE_TILE(As[cur], Bs[cur])

// ---------------- GEMM1: F = bf16( Xb @ Wt^T + bias ), M=16384 N=1024 K=1024
__global__ __launch_bounds__(512, 2) void k_gemm1(const unsigned short* __restrict__ Xb,
                                                  const unsigned short* __restrict__ Wt,
                                                  const float* __restrict__ bias,
                                                  unsigned short* __restrict__ F) {
  const int bid = blockIdx.x;                      // nwg = 256
  const int swz = (bid & 7) * 32 + (bid >> 3);     // XCD-chunked
  const int m0 = (swz >> 2) * 256, n0 = (swz & 3) * 256;
  GEMM_PREAMBLE
  GEMM_MAIN(Xb, 1024, m0, Wt, 1024, n0, 32)
  const int r4 = (lane >> 4) * 4, cl = lane & 15;
#pragma unroll
  for (int n = 0; n < 4; ++n) {
    int col = n0 + wc * 64 + n * 16 + cl;
    float bv = bias[col];
#pragma unroll
    for (int m = 0; m < 8; ++m) {
      int row = m0 + wr * 128 + m * 16 + r4;
#pragma unroll
      for (int j = 0; j < 4; ++j)
        F[(size_t)(row + j) * 1024 + col] = f2bf(acc[m][n][j] + bv);
    }
  }
}

// ---------------- GEMM2: E[b] = bf16( F F^T + distbias ), per batch 2048x2048 K=1024
__global__ __launch_bounds__(512, 2) void k_gemm2(const unsigned short* __restrict__ F,
                                                  unsigned short* __restrict__ E) {
  const int bid = blockIdx.x;                      // nwg = 512
  const int swz = (bid & 7) * 64 + (bid >> 3);     // one batch per XCD
  const int z = swz >> 6;
  const int m0 = ((swz >> 3) & 7) * 256, n0 = (swz & 7) * 256;
  const unsigned short* Fb = F + (size_t)z * 2048 * 1024;
  unsigned short* Eb = E + (size_t)z * 2048 * 2048;
  GEMM_PREAMBLE
  GEMM_MAIN(Fb, 1024, m0, Fb, 1024, n0, 32)
  const int r4 = (lane >> 4) * 4, cl = lane & 15;
#pragma unroll
  for (int m = 0; m < 8; ++m) {
    int row = m0 + wr * 128 + m * 16 + r4;
#pragma unroll
    for (int n = 0; n < 4; ++n) {
      int col = n0 + wc * 64 + n * 16 + cl;
#pragma unroll
      for (int j = 0; j < 4; ++j) {
        int rr = row + j;
        int d = rr - col; d = d < 0 ? -d : d; d = d > 10 ? 10 : d;
        Eb[(size_t)rr * 2048 + col] = f2bf(acc[m][n][j] + (float)d * 0.01f);
      }
    }
  }
}

// ---------------- row softmax on bf16 E in place (rows of 2048) ----------------
__global__ __launch_bounds__(256) void k_softmax(unsigned short* __restrict__ E) {
  unsigned short* row = E + (size_t)blockIdx.x * 2048;
  const int tid = threadIdx.x, lane = tid & 63, w = tid >> 6;
  uint4 v = *(const uint4*)(row + tid * 8);
  float f[8];
  const unsigned int* up = (const unsigned int*)&v;
  for (int i = 0; i < 4; ++i) {
    f[2*i]   = bf2f((unsigned short)(up[i] & 0xFFFF));
    f[2*i+1] = bf2f((unsigned short)(up[i] >> 16));
  }
  float mx = f[0];
  for (int i = 1; i < 8; ++i) mx = fmaxf(mx, f[i]);
  for (int s = 32; s > 0; s >>= 1) mx = fmaxf(mx, __shfl_xor(mx, s));
  __shared__ float redm[4], reds[4];
  if (lane == 0) redm[w] = mx;
  __syncthreads();
  mx = fmaxf(fmaxf(redm[0], redm[1]), fmaxf(redm[2], redm[3]));
  float p[8], sum = 0.f;
  for (int i = 0; i < 8; ++i) { p[i] = __expf(f[i] - mx); sum += p[i]; }
  for (int s = 32; s > 0; s >>= 1) sum += __shfl_xor(sum, s);
  if (lane == 0) reds[w] = sum;
  __syncthreads();
  sum = reds[0] + reds[1] + reds[2] + reds[3];
  float inv = 1.0f / sum;
  unsigned short h[8];
  for (int i = 0; i < 8; ++i) h[i] = f2bf(p[i] * inv);
  *(uint4*)(row + tid * 8) = *(uint4*)h;
}

// ---------------- GEMM3: out[b] = P @ F  (A=P [2048][2048], B=Ft [1024][2048]) fp32 out
__global__ __launch_bounds__(512, 2) void k_gemm3(const unsigned short* __restrict__ P,
                                                  const unsigned short* __restrict__ Ft,
                                                  float* __restrict__ out) {
  const int bid = blockIdx.x;                      // nwg = 256
  const int swz = (bid & 7) * 32 + (bid >> 3);     // one batch per XCD
  const int z = swz >> 5;
  const int m0 = ((swz >> 2) & 7) * 256, n0 = (swz & 3) * 256;
  const unsigned short* Pb = P + (size_t)z * 2048 * 2048;
  const unsigned short* Ftb = Ft + (size_t)z * 1024 * 2048;
  float* outb = out + (size_t)z * 2048 * 1024;
  GEMM_PREAMBLE
  GEMM_MAIN(Pb, 2048, m0, Ftb, 2048, n0, 64)
  const int r4 = (lane >> 4) * 4, cl = lane & 15;
#pragma unroll
  for (int m = 0; m < 8; ++m) {
    int row = m0 + wr * 128 + m * 16 + r4;
#pragma unroll
    for (int n = 0; n < 4; ++n) {
      int col = n0 + wc * 64 + n * 16 + cl;
#pragma unroll
      for (int j = 0; j < 4; ++j)
        outb[(size_t)(row + j) * 1024 + col] = acc[m][n][j];
    }
  }
}

extern "C" void kernel_launch(void* const* d_in, const int* in_sizes, int n_in,
                              void* d_out, int out_size, void* d_ws, size_t ws_size,
                              hipStream_t stream) {
  const float* x = (const float*)d_in[0];   // [8,2048,1024] fp32
  const float* W = (const float*)d_in[1];   // [1024,1024] fp32
  const float* b = (const float*)d_in[2];   // [1024] fp32
  float* out = (float*)d_out;               // [8,2048,1024] fp32

  // ws: Wt 2MB | F 32MB | Ft 32MB | E(bf16) 64MB | Xb 32MB  = 162 MiB
  unsigned short* Wt = (unsigned short*)d_ws;
  unsigned short* F  = (unsigned short*)((char*)d_ws + (2ull   << 20));
  unsigned short* Ft = (unsigned short*)((char*)d_ws + (34ull  << 20));
  unsigned short* E  = (unsigned short*)((char*)d_ws + (66ull  << 20));
  unsigned short* Xb = (unsigned short*)((char*)d_ws + (130ull << 20));

  k_convW  <<<dim3(16, 16),    256, 0, stream>>>(W, Wt);
  k_convX  <<<dim3(4096),      256, 0, stream>>>(x, Xb);
  k_gemm1  <<<dim3(256),       512, 0, stream>>>(Xb, Wt, b, F);
  k_transF <<<dim3(32, 16, 8), 256, 0, stream>>>(F, Ft);
  k_gemm2  <<<dim3(512),       512, 0, stream>>>(F, E);
  k_softmax<<<dim3(16384),     256, 0, stream>>>(E);
  k_gemm3  <<<dim3(256),       512, 0, stream>>>(E, Ft, out);
}

// Round 4
// 353.632 us; speedup vs baseline: 1.3306x; 1.0847x over previous
//
#include <hip/hip_runtime.h>
#include <hip/hip_bf16.h>
#include <stdint.h>

typedef __attribute__((ext_vector_type(8))) short bf16x8;
typedef __attribute__((ext_vector_type(4))) float f32x4;

static __device__ __forceinline__ unsigned short f2bf(float f) {
  union { float f; unsigned int u; } v; v.f = f;
  unsigned int u = v.u;
  u += 0x7FFFu + ((u >> 16) & 1u);   // RNE
  return (unsigned short)(u >> 16);
}
static __device__ __forceinline__ float bf2f(unsigned short h) {
  union { unsigned int u; float f; } v; v.u = ((unsigned int)h) << 16; return v.f;
}

typedef __attribute__((address_space(1))) void gvoid;
typedef __attribute__((address_space(3))) void lvoid;
static __device__ __forceinline__ void gload_lds16(const void* gp, void* lp) {
  __builtin_amdgcn_global_load_lds((gvoid*)gp, (lvoid*)lp, 16, 0, 0);
}

// ---------------- X fp32 -> Xb bf16 ----------------
__global__ __launch_bounds__(256) void k_convX(const float* __restrict__ X,
                                               unsigned short* __restrict__ Xb) {
  size_t i = ((size_t)blockIdx.x * 256 + threadIdx.x) * 8;
  const size_t stride = (size_t)4096 * 256 * 8;
  for (; i < (size_t)16777216; i += stride) {
    float4 v0 = *(const float4*)(X + i), v1 = *(const float4*)(X + i + 4);
    unsigned short h[8];
    h[0]=f2bf(v0.x); h[1]=f2bf(v0.y); h[2]=f2bf(v0.z); h[3]=f2bf(v0.w);
    h[4]=f2bf(v1.x); h[5]=f2bf(v1.y); h[6]=f2bf(v1.z); h[7]=f2bf(v1.w);
    *(uint4*)(Xb + i) = *(uint4*)h;
  }
}

// ---------------- W [K][N] fp32 -> Wt [N][K] bf16 ----------------
__global__ __launch_bounds__(256) void k_convW(const float* __restrict__ W,
                                               unsigned short* __restrict__ Wt) {
  __shared__ __align__(16) unsigned short lds[64][72];
  const int tid = threadIdx.x;
  const int n0 = blockIdx.x * 64, k0 = blockIdx.y * 64;
  for (int i = 0; i < 4; ++i) {
    int c = i * 256 + tid;
    int r = c >> 4, c4 = (c & 15) * 4;
    float4 v = *(const float4*)(W + (size_t)(k0 + r) * 1024 + n0 + c4);
    unsigned short* p = &lds[r][c4];
    p[0] = f2bf(v.x); p[1] = f2bf(v.y); p[2] = f2bf(v.z); p[3] = f2bf(v.w);
  }
  __syncthreads();
  for (int i = 0; i < 2; ++i) {
    int c = i * 256 + tid;
    int n = c >> 3, k8 = (c & 7) * 8;
    unsigned short tmp[8];
    for (int j = 0; j < 8; ++j) tmp[j] = lds[k8 + j][n];
    *(uint4*)(Wt + (size_t)(n0 + n) * 1024 + k0 + k8) = *(uint4*)tmp;
  }
}

// ---------------- F [S][D] bf16 -> Ft [D][S] bf16, per batch ----------------
__global__ __launch_bounds__(256) void k_transF(const unsigned short* __restrict__ F,
                                                unsigned short* __restrict__ Ft) {
  __shared__ __align__(16) unsigned short lds[64][72];
  const int tid = threadIdx.x;
  const int t0 = blockIdx.x * 64, d0 = blockIdx.y * 64;
  const unsigned short* Fb = F + (size_t)blockIdx.z * 2048 * 1024;
  unsigned short* Ftb = Ft + (size_t)blockIdx.z * 1024 * 2048;
  for (int i = 0; i < 2; ++i) {
    int c = i * 256 + tid;
    int r = c >> 3, d8 = (c & 7) * 8;
    *(uint4*)(&lds[r][d8]) = *(const uint4*)(Fb + (size_t)(t0 + r) * 1024 + d0 + d8);
  }
  __syncthreads();
  for (int i = 0; i < 2; ++i) {
    int c = i * 256 + tid;
    int d = c >> 3, t8 = (c & 7) * 8;
    unsigned short tmp[8];
    for (int j = 0; j < 8; ++j) tmp[j] = lds[t8 + j][d];
    *(uint4*)(Ftb + (size_t)(d0 + d) * 2048 + t0 + t8) = *(uint4*)tmp;
  }
}

// =====================================================================
// 256x256 tile, BK=32, 4-buffer LDS ring (128 KiB), 8 waves (2M x 4N).
// Per K-tile: 2 phases {ds_read frags | stage 2 gload_lds | barrier |
// lgkmcnt(0) | setprio(1) 16 MFMA setprio(0) | barrier}; vmcnt(8) once
// per K-tile (counted, never 0 in loop). T2 slot-XOR swizzle both sides.
// =====================================================================

template<int NT>
__device__ __forceinline__ void gemm_core(
    const unsigned short* __restrict__ Ag, int lda, int ar0,
    const unsigned short* __restrict__ Bg, int ldb, int br0,
    unsigned short* __restrict__ As, unsigned short* __restrict__ Bs,
    f32x4 (&acc)[8][4]) {
  const int tid = threadIdx.x, lane = tid & 63, wid = tid >> 6;
  const int wr = wid >> 2, wc = wid & 3;
  const int rl = lane & 15;
  // read-side swizzle: slot_eff = (lane>>4) ^ swz(row), swz(r)=(r&3)^((r>>2)&3)
  const int rslot = (((lane >> 4) ^ (lane & 3) ^ ((lane >> 2) & 3))) * 8;
  // stage-side: thread's LDS slot (tid&3) must fetch global slot (tid&3)^swz(row)
  const int q = tid >> 2;                          // row within 128-row chunk
  const int sslot = (((tid & 3) ^ (q & 3) ^ ((q >> 2) & 3))) * 8;

#define STAGE_T(dstbase, src, ld, r0, kt)                                      \
  _Pragma("unroll")                                                            \
  for (int r_ = 0; r_ < 2; ++r_)                                               \
    gload_lds16((src) + (size_t)((r0) + r_ * 128 + q) * (ld) + (kt) * 32 + sslot, \
                (char*)(dstbase) + r_ * 8192 + wid * 1024);

  // prologue: stage K-tiles 0,1,2 (12 loads/thread)
  STAGE_T(As + 0 * 8192, Ag, lda, ar0, 0)
  STAGE_T(Bs + 0 * 8192, Bg, ldb, br0, 0)
  STAGE_T(As + 1 * 8192, Ag, lda, ar0, 1)
  STAGE_T(Bs + 1 * 8192, Bg, ldb, br0, 1)
  STAGE_T(As + 2 * 8192, Ag, lda, ar0, 2)
  STAGE_T(Bs + 2 * 8192, Bg, ldb, br0, 2)
  asm volatile("s_waitcnt vmcnt(8)" ::: "memory");   // K-tile 0 landed
  __builtin_amdgcn_s_barrier();

  bf16x8 a[4], b[4], a2[4];
  for (int t = 0; t < NT; ++t) {
    const int sl = t & 3;
    const int ps = (t + 3 < NT) ? (t + 3) : (NT - 1);  // clamped prefetch (junk ok)
    const int psl = (t + 3) & 3;
    const unsigned short* Ab = As + sl * 8192;
    const unsigned short* Bb = Bs + sl * 8192;
    // ---- phase 0: frags m0..3 + all B, stage A of tile t+3, MFMA quad 0
#pragma unroll
    for (int m = 0; m < 4; ++m)
      a[m] = *(const bf16x8*)(Ab + (wr * 128 + m * 16 + rl) * 32 + rslot);
#pragma unroll
    for (int n = 0; n < 4; ++n)
      b[n] = *(const bf16x8*)(Bb + (wc * 64 + n * 16 + rl) * 32 + rslot);
    STAGE_T(As + psl * 8192, Ag, lda, ar0, ps)
    __builtin_amdgcn_s_barrier();
    asm volatile("s_waitcnt lgkmcnt(0)" ::: "memory");
    __builtin_amdgcn_s_setprio(1);
#pragma unroll
    for (int m = 0; m < 4; ++m)
#pragma unroll
      for (int n = 0; n < 4; ++n)
        acc[m][n] = __builtin_amdgcn_mfma_f32_16x16x32_bf16(a[m], b[n], acc[m][n], 0, 0, 0);
    __builtin_amdgcn_s_setprio(0);
    __builtin_amdgcn_s_barrier();
    // ---- phase 1: frags m4..7 (B reused), stage B of tile t+3, MFMA quad 1
#pragma unroll
    for (int m = 0; m < 4; ++m)
      a2[m] = *(const bf16x8*)(Ab + (wr * 128 + (m + 4) * 16 + rl) * 32 + rslot);
    STAGE_T(Bs + psl * 8192, Bg, ldb, br0, ps)
    __builtin_amdgcn_s_barrier();
    asm volatile("s_waitcnt lgkmcnt(0)" ::: "memory");
    __builtin_amdgcn_s_setprio(1);
#pragma unroll
    for (int m = 0; m < 4; ++m)
#pragma unroll
      for (int n = 0; n < 4; ++n)
        acc[m + 4][n] = __builtin_amdgcn_mfma_f32_16x16x32_bf16(a2[m], b[n], acc[m + 4][n], 0, 0, 0);
    __builtin_amdgcn_s_setprio(0);
    asm volatile("s_waitcnt vmcnt(8)" ::: "memory");   // K-tile t+1 landed
    __builtin_amdgcn_s_barrier();
  }
  asm volatile("s_waitcnt vmcnt(0)" ::: "memory");     // drain before LDS dies
#undef STAGE_T
}

// ---------------- GEMM1: F = bf16( Xb @ Wt^T + bias ) ----------------
__global__ __launch_bounds__(512, 2) void k_gemm1(const unsigned short* __restrict__ Xb,
                                                  const unsigned short* __restrict__ Wt,
                                                  const float* __restrict__ bias,
                                                  unsigned short* __restrict__ F) {
  __shared__ __align__(16) unsigned short As[4 * 8192];
  __shared__ __align__(16) unsigned short Bs[4 * 8192];
  const int bid = blockIdx.x;                      // nwg = 256
  const int swz = (bid & 7) * 32 + (bid >> 3);
  const int m0 = (swz >> 2) * 256, n0 = (swz & 3) * 256;
  f32x4 acc[8][4] = {};
  gemm_core<32>(Xb, 1024, m0, Wt, 1024, n0, As, Bs, acc);
  const int tid = threadIdx.x, lane = tid & 63, wid = tid >> 6;
  const int wr = wid >> 2, wc = wid & 3;
  const int r4 = (lane >> 4) * 4, cl = lane & 15;
#pragma unroll
  for (int n = 0; n < 4; ++n) {
    int col = n0 + wc * 64 + n * 16 + cl;
    float bv = bias[col];
#pragma unroll
    for (int m = 0; m < 8; ++m) {
      int row = m0 + wr * 128 + m * 16 + r4;
#pragma unroll
      for (int j = 0; j < 4; ++j)
        F[(size_t)(row + j) * 1024 + col] = f2bf(acc[m][n][j] + bv);
    }
  }
}

// ---------------- GEMM2: E[b] = bf16( F F^T + distbias ) ----------------
__global__ __launch_bounds__(512, 2) void k_gemm2(const unsigned short* __restrict__ F,
                                                  unsigned short* __restrict__ E) {
  __shared__ __align__(16) unsigned short As[4 * 8192];
  __shared__ __align__(16) unsigned short Bs[4 * 8192];
  const int bid = blockIdx.x;                      // nwg = 512
  const int swz = (bid & 7) * 64 + (bid >> 3);     // one batch per XCD
  const int z = swz >> 6;
  const int m0 = ((swz >> 3) & 7) * 256, n0 = (swz & 7) * 256;
  const unsigned short* Fb = F + (size_t)z * 2048 * 1024;
  unsigned short* Eb = E + (size_t)z * 2048 * 2048;
  f32x4 acc[8][4] = {};
  gemm_core<32>(Fb, 1024, m0, Fb, 1024, n0, As, Bs, acc);
  const int tid = threadIdx.x, lane = tid & 63, wid = tid >> 6;
  const int wr = wid >> 2, wc = wid & 3;
  const int r4 = (lane >> 4) * 4, cl = lane & 15;
#pragma unroll
  for (int m = 0; m < 8; ++m) {
    int row = m0 + wr * 128 + m * 16 + r4;
#pragma unroll
    for (int n = 0; n < 4; ++n) {
      int col = n0 + wc * 64 + n * 16 + cl;
#pragma unroll
      for (int j = 0; j < 4; ++j) {
        int rr = row + j;
        int d = rr - col; d = d < 0 ? -d : d; d = d > 10 ? 10 : d;
        Eb[(size_t)rr * 2048 + col] = f2bf(acc[m][n][j] + (float)d * 0.01f);
      }
    }
  }
}

// ---------------- row softmax on bf16 E in place ----------------
__global__ __launch_bounds__(256) void k_softmax(unsigned short* __restrict__ E) {
  unsigned short* row = E + (size_t)blockIdx.x * 2048;
  const int tid = threadIdx.x, lane = tid & 63, w = tid >> 6;
  uint4 v = *(const uint4*)(row + tid * 8);
  float f[8];
  const unsigned int* up = (const unsigned int*)&v;
  for (int i = 0; i < 4; ++i) {
    f[2*i]   = bf2f((unsigned short)(up[i] & 0xFFFF));
    f[2*i+1] = bf2f((unsigned short)(up[i] >> 16));
  }
  float mx = f[0];
  for (int i = 1; i < 8; ++i) mx = fmaxf(mx, f[i]);
  for (int s = 32; s > 0; s >>= 1) mx = fmaxf(mx, __shfl_xor(mx, s));
  __shared__ float redm[4], reds[4];
  if (lane == 0) redm[w] = mx;
  __syncthreads();
  mx = fmaxf(fmaxf(redm[0], redm[1]), fmaxf(redm[2], redm[3]));
  float p[8], sum = 0.f;
  for (int i = 0; i < 8; ++i) { p[i] = __expf(f[i] - mx); sum += p[i]; }
  for (int s = 32; s > 0; s >>= 1) sum += __shfl_xor(sum, s);
  if (lane == 0) reds[w] = sum;
  __syncthreads();
  sum = reds[0] + reds[1] + reds[2] + reds[3];
  float inv = 1.0f / sum;
  unsigned short h[8];
  for (int i = 0; i < 8; ++i) h[i] = f2bf(p[i] * inv);
  *(uint4*)(row + tid * 8) = *(uint4*)h;
}

// ---------------- GEMM3: out[b] = P @ F (B = Ft), fp32 out ----------------
__global__ __launch_bounds__(512, 2) void k_gemm3(const unsigned short* __restrict__ P,
                                                  const unsigned short* __restrict__ Ft,
                                                  float* __restrict__ out) {
  __shared__ __align__(16) unsigned short As[4 * 8192];
  __shared__ __align__(16) unsigned short Bs[4 * 8192];
  const int bid = blockIdx.x;                      // nwg = 256
  const int swz = (bid & 7) * 32 + (bid >> 3);     // one batch per XCD
  const int z = swz >> 5;
  const int m0 = ((swz >> 2) & 7) * 256, n0 = (swz & 3) * 256;
  const unsigned short* Pb = P + (size_t)z * 2048 * 2048;
  const unsigned short* Ftb = Ft + (size_t)z * 1024 * 2048;
  float* outb = out + (size_t)z * 2048 * 1024;
  f32x4 acc[8][4] = {};
  gemm_core<64>(Pb, 2048, m0, Ftb, 2048, n0, As, Bs, acc);
  const int tid = threadIdx.x, lane = tid & 63, wid = tid >> 6;
  const int wr = wid >> 2, wc = wid & 3;
  const int r4 = (lane >> 4) * 4, cl = lane & 15;
#pragma unroll
  for (int m = 0; m < 8; ++m) {
    int row = m0 + wr * 128 + m * 16 + r4;
#pragma unroll
    for (int n = 0; n < 4; ++n) {
      int col = n0 + wc * 64 + n * 16 + cl;
#pragma unroll
      for (int j = 0; j < 4; ++j)
        outb[(size_t)(row + j) * 1024 + col] = acc[m][n][j];
    }
  }
}

extern "C" void kernel_launch(void* const* d_in, const int* in_sizes, int n_in,
                              void* d_out, int out_size, void* d_ws, size_t ws_size,
                              hipStream_t stream) {
  const float* x = (const float*)d_in[0];
  const float* W = (const float*)d_in[1];
  const float* b = (const float*)d_in[2];
  float* out = (float*)d_out;

  // ws: Wt 2MB | F 32MB | Ft 32MB | E(bf16) 64MB | Xb 32MB
  unsigned short* Wt = (unsigned short*)d_ws;
  unsigned short* F  = (unsigned short*)((char*)d_ws + (2ull   << 20));
  unsigned short* Ft = (unsigned short*)((char*)d_ws + (34ull  << 20));
  unsigned short* E  = (unsigned short*)((char*)d_ws + (66ull  << 20));
  unsigned short* Xb = (unsigned short*)((char*)d_ws + (130ull << 20));

  k_convW  <<<dim3(16, 16),    256, 0, stream>>>(W, Wt);
  k_convX  <<<dim3(4096),      256, 0, stream>>>(x, Xb);
  k_gemm1  <<<dim3(256),       512, 0, stream>>>(Xb, Wt, b, F);
  k_transF <<<dim3(32, 16, 8), 256, 0, stream>>>(F, Ft);
  k_gemm2  <<<dim3(512),       512, 0, stream>>>(F, E);
  k_softmax<<<dim3(16384),     256, 0, stream>>>(E);
  k_gemm3  <<<dim3(256),       512, 0, stream>>>(E, Ft, out);
}